// Round 8
// baseline (2261.916 us; speedup 1.0000x reference)
//
#include <hip/hip_runtime.h>
#include <hip/hip_bf16.h>

// B=8, T=2048, E=1024 single-head attention, bf16 MFMA pipeline, round 10:
// gemm_nt restructured for 2 blocks/CU TLP (diagnosis: 40% MfmaUtil across
// 4 schedule variants = lockstep read-burst/MFMA-burst serialization;
// second resident block fills the gaps). BK=32, A-ring 3x16KB + B-ring
// 2x16KB = 80 KB LDS (2 blocks = 160 KB/CU exactly). Same verified chunk
// swizzle and 64-B-row unit geometry. 2 phases/K-tile; counted vmcnt(4)
// at p2 confirms tile t+1 (issue ages 3/2 phases); never drains mid-loop.
// Fused softmax + fused V^T (4x64-col passes) + prep/memset kept from r9.
typedef __attribute__((ext_vector_type(8))) short short8;
typedef __attribute__((ext_vector_type(8))) unsigned short ushortx8;
typedef __attribute__((ext_vector_type(4))) unsigned short ushortx4;
typedef __attribute__((ext_vector_type(4))) float floatx4;
typedef __attribute__((ext_vector_type(2))) unsigned int uint2v;

#define NB 8
#define NT 2048
#define NE 1024

__device__ __forceinline__ unsigned short f2bf(float f){
  unsigned int u = __builtin_bit_cast(unsigned int, f);
  u += 0x7FFFu + ((u >> 16) & 1u);          // RNE; inputs finite
  return (unsigned short)(u >> 16);
}

__device__ __forceinline__ void async16(void* lds, const void* g){
  __builtin_amdgcn_global_load_lds(
      (const __attribute__((address_space(1))) unsigned int*)g,
      (__attribute__((address_space(3))) unsigned int*)lds, 16, 0, 0);
}

#define MFMA16(d, va, vb) \
  d = __builtin_amdgcn_mfma_f32_16x16x32_bf16(va, vb, d, 0, 0, 0)

// ---------------- fp32 -> bf16 convert, 3 sources (q,k,v) ----------------
__global__ __launch_bounds__(256) void cvt3(const float* __restrict__ a0,
                                            const float* __restrict__ a1,
                                            const float* __restrict__ a2,
                                            unsigned short* __restrict__ out,
                                            int n4_per){
  const float* src = blockIdx.y == 0 ? a0 : (blockIdx.y == 1 ? a1 : a2);
  unsigned short* dst = out + (size_t)blockIdx.y * (size_t)n4_per * 4;
  int i = blockIdx.x * 256 + threadIdx.x;
  if (i < n4_per){
    floatx4 f = ((const floatx4*)src)[i];
    ushortx4 o;
    o.x = f2bf(f.x); o.y = f2bf(f.y); o.z = f2bf(f.z); o.w = f2bf(f.w);
    *(ushortx4*)(dst + (size_t)i * 4) = o;
  }
}

// ------ prep: weights fp32->bf16 (blocks 0..3071) + mask bitpack (3072..3327) ------
__global__ __launch_bounds__(256) void prep(const float* __restrict__ w0,
                                            const float* __restrict__ w1,
                                            const float* __restrict__ w2,
                                            unsigned short* __restrict__ wout,
                                            const int* __restrict__ m,
                                            unsigned long long* __restrict__ bits){
  int bx = blockIdx.x;
  if (bx < 3072){
    int y = bx >> 10;
    int i = ((bx & 1023) << 8) + threadIdx.x;         // 0..262143 per weight
    const float* src = y == 0 ? w0 : (y == 1 ? w1 : w2);
    floatx4 f = ((const floatx4*)src)[i];
    ushortx4 o;
    o.x = f2bf(f.x); o.y = f2bf(f.y); o.z = f2bf(f.z); o.w = f2bf(f.w);
    *(ushortx4*)(wout + (size_t)y * (NE * NE) + (size_t)i * 4) = o;
  } else {
    int t = ((bx - 3072) << 8) + threadIdx.x;         // 0..65535 words
    const int4* p = (const int4*)(m + (size_t)t * 64);
    unsigned long long w = 0;
    #pragma unroll
    for (int jj = 0; jj < 16; jj++){
      int4 v = p[jj];
      w |= (unsigned long long)(v.x != 0) << (jj * 4 + 0);
      w |= (unsigned long long)(v.y != 0) << (jj * 4 + 1);
      w |= (unsigned long long)(v.z != 0) << (jj * 4 + 2);
      w |= (unsigned long long)(v.w != 0) << (jj * 4 + 3);
    }
    bits[t] = w;
  }
}

// ---------------- NT GEMM: C[m,n] = sum_k A[m,k]*B[n,k], all bf16 in ----------------
// Tile 256x256, BK=32, 512 threads = 8 waves (wm=wave>>2 M, wn=wave&3 N);
// per-wave 128x64 output = acc[8][4] of 16x16x32 MFMAs (32 MFMA/K-tile).
// LDS 80 KB: A-ring 3 x 16 KB @ {0,16K,32K}, B-ring 2 x 16 KB @ {48K,64K}.
// Unit = 256 rows x 32 bf16 (64-B rows); chunk c of row r at slot
// c^((r>>1)&3) (verified 0-conflict). Staging: linear-LDS global_load_lds,
// inverse swizzle on the per-lane GLOBAL address.
// Per K-tile t (read A slot t%3, B slot t&1):
//  p1: stage A(t+2)->(t+2)%3 [freed @(t-1).p2 bar]; read a0-3,b0-3;
//      lgkm0+bar; 16 MFMA (mi0-3)
//  p2: stage B(t+2)->t&1 [freed @t.p1 bar]; read a4-7;
//      vmcnt(4)+lgkm0+bar [confirms A(t+1),B(t+1); ages 3/2 phases];
//      16 MFMA (mi4-7)
// Tail: t+2==NK: p2 vmcnt(0); t+1==NK: lgkm0 only. Prologue: stage
// A0,B0,A1,B1; vmcnt(4)+bar (A0,B0 resident; A1,B1 in flight).
// EPI 0: bf16 store; z==2 && trOut: fused V^T via 4x64-col LDS passes.
// EPI 1: e = mask ? exp(v/32) : 0, bf16 store + atomic row sums.
// EPI 2: fp32 store scaled by 1/rowsum.
template<int EPI>
__global__ __launch_bounds__(512, 4) void gemm_nt(
    const unsigned short* __restrict__ A, long strideA,
    const unsigned short* __restrict__ B, long strideB,
    void* __restrict__ Out, long strideOutBytes,
    const unsigned long long* __restrict__ mbits,
    float* __restrict__ rowsums,
    unsigned short* __restrict__ trOut,
    int K, int gx, int gy)
{
  __shared__ __attribute__((aligned(16))) char Lds[81920];
  const int tid = threadIdx.x;
  const int lane = tid & 63, wave = tid >> 6;

  // XCD-aware decode: L%8 = XCD; all gx n-tiles of one A-strip on one XCD.
  int L = blockIdx.x;
  int xcd = L & 7, tt = L >> 3;
  int x = tt % gx;
  int strip = xcd + ((tt / gx) << 3);
  int y = strip % gy, z = strip / gy;
  const int m0 = y << 8, n0 = x << 8;
  const int Nn = gx << 8;

  const unsigned short* Az = A + (size_t)z * strideA;
  const unsigned short* Bz = B + (size_t)z * strideB;

  // Staging: unit = 16 KB = 1024 slots of 16B; thread covers slots tid and
  // tid+512. slot s: r = s>>2 (row; +128 for the second), cs = s&3,
  // logical chunk c = cs ^ ((r>>1)&3)  [invariant under r+128].
  const long rowb  = (long)K * 2;       // bytes per A/B row
  const long rs128 = rowb << 7;         // 128 rows
  const int r0 = tid >> 2;
  const int c0 = (tid & 3) ^ ((r0 >> 1) & 3);
  const char* pA = (const char*)Az + (size_t)(m0 + r0) * rowb + (c0 << 4);
  const char* pB = (const char*)Bz + (size_t)(n0 + r0) * rowb + (c0 << 4);
  const int stg = tid << 4;

  auto stageU = [&](const char*& g, int ldsoff){
    async16(Lds + ldsoff + stg,        g);
    async16(Lds + ldsoff + stg + 8192, g + rs128);
    g += 64;                            // advance one K-tile (BK=32 bf16)
  };

  // Fragment reads: row = (warp base) + mi*16 + lm, logical chunk qd at
  // physical slot qd ^ ((row>>1)&3) = qd ^ ((lm>>1)&3).
  const int lm = lane & 15, qd = lane >> 4;
  const int wm = wave >> 2, wn = wave & 3;          // 2 (M) x 4 (N)
  const int fsw  = (qd ^ ((lm >> 1) & 3)) << 4;
  const int aoff = ((wm << 7) + lm) * 64 + fsw;     // + mi*1024 + ring base
  const int boff = ((wn << 6) + lm) * 64 + fsw;     // + ni*1024 + ring base

  floatx4 acc[8][4];
  floatx4 zero4 = {0.f, 0.f, 0.f, 0.f};
  #pragma unroll
  for (int a = 0; a < 8; a++)
    #pragma unroll
    for (int b = 0; b < 4; b++) acc[a][b] = zero4;

  const int NK = K >> 5;

  // Prologue: A(0),B(0),A(1),B(1); confirm A0,B0 (oldest 4), leave 4 in flight.
  stageU(pA, 0);                // A(0) -> slot A0
  stageU(pB, 49152);            // B(0) -> slot B0
  stageU(pA, 16384);            // A(1) -> slot A1
  stageU(pB, 49152 + 16384);    // B(1) -> slot B1
  asm volatile("s_waitcnt vmcnt(4)\n\ts_barrier" ::: "memory");

  short8 a[4], b[4];
  int ia = 0;                   // t % 3 (A-ring read index)
  for (int t = 0; t < NK; ++t){
    const int rbA = ia << 14;
    const int rbB = 49152 + ((t & 1) << 14);
    const int sA  = (ia >= 1 ? ia - 1 : 2) << 14;   // slot (t+2)%3

    // ---- phase 1: mi 0-3 + all B ----
    if (t + 2 < NK) stageU(pA, sA);
    #pragma unroll
    for (int j = 0; j < 4; j++) a[j] = *(const short8*)(Lds + rbA + aoff + j * 1024);
    #pragma unroll
    for (int n = 0; n < 4; n++) b[n] = *(const short8*)(Lds + rbB + boff + n * 1024);
    asm volatile("s_waitcnt lgkmcnt(0)\n\ts_barrier" ::: "memory");
    __builtin_amdgcn_sched_barrier(0);
    __builtin_amdgcn_s_setprio(1);
    #pragma unroll
    for (int j = 0; j < 4; j++)
      #pragma unroll
      for (int n = 0; n < 4; n++) MFMA16(acc[j][n], a[j], b[n]);
    __builtin_amdgcn_s_setprio(0);

    // ---- phase 2: mi 4-7; counted vmcnt confirms tile t+1 ----
    if (t + 2 < NK) stageU(pB, rbB);                // B(t+2) -> slot t&1
    #pragma unroll
    for (int j = 0; j < 4; j++) a[j] = *(const short8*)(Lds + rbA + aoff + (4 + j) * 1024);
    if (t + 2 < NK)
      asm volatile("s_waitcnt vmcnt(4) lgkmcnt(0)\n\ts_barrier" ::: "memory");
    else if (t + 1 < NK)
      asm volatile("s_waitcnt vmcnt(0) lgkmcnt(0)\n\ts_barrier" ::: "memory");
    else
      asm volatile("s_waitcnt lgkmcnt(0)\n\ts_barrier" ::: "memory");
    __builtin_amdgcn_sched_barrier(0);
    __builtin_amdgcn_s_setprio(1);
    #pragma unroll
    for (int j = 0; j < 4; j++)
      #pragma unroll
      for (int n = 0; n < 4; n++) MFMA16(acc[4 + j][n], a[j], b[n]);
    __builtin_amdgcn_s_setprio(0);

    ia = (ia == 2) ? 0 : ia + 1;
  }

  // Epilogue. C/D layout: col = lane&15, row = (lane>>4)*4 + i  (m89/m91).
  char* OutZ = (char*)Out + (size_t)z * strideOutBytes;
  const int colbase = n0 + (wn << 6);
  if constexpr (EPI == 1){
    const int wcol = colbase >> 6;
    #pragma unroll
    for (int mi = 0; mi < 8; mi++){
      #pragma unroll
      for (int i = 0; i < 4; i++){
        int row = m0 + (wm << 7) + mi * 16 + qd * 4 + i;
        unsigned long long w = mbits[(size_t)row * (NT / 64) + wcol];
        unsigned short* po = (unsigned short*)OutZ + (size_t)row * Nn + colbase;
        float rsum = 0.f;
        #pragma unroll
        for (int ni = 0; ni < 4; ni++){
          float vv = acc[mi][ni][i];
          float e = ((w >> (ni * 16 + lm)) & 1ull) ? __expf(vv * 0.03125f) : 0.f;
          rsum += e;
          po[ni * 16 + lm] = f2bf(e);
        }
        rsum += __shfl_xor(rsum, 1, 64);
        rsum += __shfl_xor(rsum, 2, 64);
        rsum += __shfl_xor(rsum, 4, 64);
        rsum += __shfl_xor(rsum, 8, 64);
        if (lm == 0) atomicAdd(rowsums + ((size_t)z << 11) + row, rsum);
      }
    }
  } else if constexpr (EPI == 2){
    #pragma unroll
    for (int mi = 0; mi < 8; mi++){
      #pragma unroll
      for (int i = 0; i < 4; i++){
        int row = m0 + (wm << 7) + mi * 16 + qd * 4 + i;
        float inv = 1.0f / rowsums[((size_t)z << 11) + row];
        #pragma unroll
        for (int ni = 0; ni < 4; ni++){
          int col = colbase + ni * 16 + lm;
          ((float*)OutZ)[(size_t)row * Nn + col] = acc[mi][ni][i] * inv;
        }
      }
    }
  } else {
    if (trOut != nullptr && z == 2){
      // Fused V^T in 4 passes of 64 cols (pass p = wave group wn==p):
      // acc -> LDS [col][token] (528-B padded rows) -> coalesced 16B stores.
      int bb = m0 >> 11, tb = m0 & 2047;             // batch, token base
      #pragma unroll
      for (int pass = 0; pass < 4; pass++){
        if (wn == pass){
          #pragma unroll
          for (int mi = 0; mi < 8; mi++){
            int row0 = (wm << 7) + mi * 16 + qd * 4;  // token within tile
            #pragma unroll
            for (int ni = 0; ni < 4; ni++){
              int col = ni * 16 + lm;                 // 0..63 within pass
              unsigned int lo = (unsigned int)f2bf(acc[mi][ni][0]) |
                                ((unsigned int)f2bf(acc[mi][ni][1]) << 16);
              unsigned int hi = (unsigned int)f2bf(acc[mi][ni][2]) |
                                ((unsigned int)f2bf(acc[mi][ni][3]) << 16);
              uint2v p; p.x = lo; p.y = hi;
              *(uint2v*)(Lds + col * 528 + row0 * 2) = p;
            }
          }
        }
        __syncthreads();
        unsigned short* base = trOut + (size_t)bb * NE * NT +
                               (size_t)(n0 + pass * 64) * NT + tb;
        #pragma unroll
        for (int k2 = 0; k2 < 4; k2++){
          int gid = (k2 << 9) + tid;                  // 0..2047
          int col = gid >> 5, chk = gid & 31;         // 64 cols x 32 chunks
          ushortx8 vv = *(const ushortx8*)(Lds + col * 528 + (chk << 4));
          *(ushortx8*)(base + (size_t)col * NT + (chk << 3)) = vv;
        }
        __syncthreads();
      }
    } else {
      #pragma unroll
      for (int mi = 0; mi < 8; mi++){
        #pragma unroll
        for (int i = 0; i < 4; i++){
          int row = m0 + (wm << 7) + mi * 16 + qd * 4 + i;
          #pragma unroll
          for (int ni = 0; ni < 4; ni++){
            int col = colbase + ni * 16 + lm;
            ((unsigned short*)OutZ)[(size_t)row * Nn + col] = f2bf(acc[mi][ni][i]);
          }
        }
      }
    }
  }
}

extern "C" void kernel_launch(void* const* d_in, const int* in_sizes, int n_in,
                              void* d_out, int out_size, void* d_ws, size_t ws_size,
                              hipStream_t stream){
  const float* q  = (const float*)d_in[0];
  const float* k  = (const float*)d_in[1];
  const float* v  = (const float*)d_in[2];
  const int* mask = (const int*)d_in[3];
  const float* Wq = (const float*)d_in[4];
  const float* Wk = (const float*)d_in[5];
  const float* Wv = (const float*)d_in[6];

  const size_t BTE = (size_t)NB * NT * NE;     // 16,777,216
  unsigned short* ws   = (unsigned short*)d_ws;
  unsigned short* QKVp = ws;                                    // [3][B*T][E] (V slot holds V^T)
  unsigned short* Sb   = ws + 3 * BTE + BTE;                    // [B][T][T]
  unsigned short* Qin  = ws + 3 * BTE;                          // [3][B*T][E] bf16 inputs
  unsigned short* Wb   = ws + 3 * BTE + BTE + (size_t)NB * NT * NT;  // [3][E][E]
  unsigned long long* mbits = (unsigned long long*)(Wb + (size_t)3 * NE * NE);
  // rowsums [NB][NT] f32 (64 KB) overlays Wb (dead after projections).
  float* rowsums = (float*)Wb;

  unsigned short* Qp  = QKVp;
  unsigned short* Kp  = QKVp + BTE;
  unsigned short* VpT = QKVp + 2 * BTE;        // [B][E][T], written by proj epilogue

  // 1) fp32 -> bf16: inputs q,k,v (Qin aliases the region later used by Sb)
  cvt3<<<dim3(16384, 3), 256, 0, stream>>>(q, k, v, Qin, (int)(BTE / 4));
  // 2) weights -> bf16 + mask -> bitmask, one dispatch
  prep<<<3328, 256, 0, stream>>>(Wq, Wk, Wv, Wb, mask, mbits);

  // 3) projections: [3 x] (16384 x 1024 x 1024); gx=4, gy=64, gz=3.
  //    z==2 (V) writes V^T into VpT via fused LDS transpose.
  gemm_nt<0><<<768, 512, 0, stream>>>(
      Qin, (long)BTE, Wb, (long)NE * NE,
      QKVp, (long)BTE * 2, nullptr, nullptr, VpT, NE, 4, 64);

  // 4) zero rowsums (Wb dead now; must precede QK^T's atomics)
  hipMemsetAsync(rowsums, 0, (size_t)NB * NT * sizeof(float), stream);

  // 5) S' = mask ? exp(QK^T/32) : 0, + per-row sums; gx=8, gy=8, gz=8
  gemm_nt<1><<<512, 512, 0, stream>>>(
      Qp, (long)NT * NE, Kp, (long)NT * NE,
      Sb, (long)NT * NT * 2, mbits, rowsums, nullptr, NE, 8, 8);

  // 6) O = (S' V) / rowsum; gx=4, gy=8, gz=8, fp32 out
  gemm_nt<2><<<256, 512, 0, stream>>>(
      Sb, (long)NT * NT, VpT, (long)NE * NT,
      d_out, (long)NT * NE * 4, nullptr, rowsums, nullptr, NT, 4, 8);
}

// Round 9
// 511.061 us; speedup vs baseline: 4.4259x; 4.4259x over previous
//
#include <hip/hip_runtime.h>
#include <hip/hip_bf16.h>

// B=8, T=2048, E=1024 single-head attention, bf16 MFMA pipeline, round 11:
// = round 9 (best verified: 498 µs) with cvt3+prep merged into one preall
// dispatch (block-range split: q/k/v cvt | weight cvt | mask pack) so the
// independent BW streams overlap instead of serializing across launches.
// Round-10's 2-blocks/CU attempt is abandoned: launch_bounds(512,4) caps
// regs at 128 < acc's 128+overhead -> accumulator spilled to scratch
// (VGPR 92->64, WRITE 98MB->2.5GB). The 256^2 tile is structurally
// 1 block/CU; small-tile multi-block structures ceiling lower (~900 TF).
typedef __attribute__((ext_vector_type(8))) short short8;
typedef __attribute__((ext_vector_type(8))) unsigned short ushortx8;
typedef __attribute__((ext_vector_type(4))) unsigned short ushortx4;
typedef __attribute__((ext_vector_type(4))) float floatx4;
typedef __attribute__((ext_vector_type(2))) unsigned int uint2v;

#define NB 8
#define NT 2048
#define NE 1024

__device__ __forceinline__ unsigned short f2bf(float f){
  unsigned int u = __builtin_bit_cast(unsigned int, f);
  u += 0x7FFFu + ((u >> 16) & 1u);          // RNE; inputs finite
  return (unsigned short)(u >> 16);
}

__device__ __forceinline__ void async16(void* lds, const void* g){
  __builtin_amdgcn_global_load_lds(
      (const __attribute__((address_space(1))) unsigned int*)g,
      (__attribute__((address_space(3))) unsigned int*)lds, 16, 0, 0);
}

#define MFMA16(d, va, vb) \
  d = __builtin_amdgcn_mfma_f32_16x16x32_bf16(va, vb, d, 0, 0, 0)

// ---- preall: q/k/v fp32->bf16 (blocks 0..49151), weights fp32->bf16
// ---- (49152..52223), mask bitpack (52224..52479) — one dispatch, BW-overlapped.
__global__ __launch_bounds__(256) void preall(const float* __restrict__ q,
                                              const float* __restrict__ k,
                                              const float* __restrict__ v,
                                              unsigned short* __restrict__ qkv,
                                              const float* __restrict__ w0,
                                              const float* __restrict__ w1,
                                              const float* __restrict__ w2,
                                              unsigned short* __restrict__ wout,
                                              const int* __restrict__ m,
                                              unsigned long long* __restrict__ bits){
  const size_t BTE = (size_t)NB * NT * NE;
  int bx = blockIdx.x;
  if (bx < 49152){
    int y = bx >> 14;                                  // source index
    int i = ((bx & 16383) << 8) + threadIdx.x;         // < BTE/4
    const float* src = y == 0 ? q : (y == 1 ? k : v);
    floatx4 f = ((const floatx4*)src)[i];
    ushortx4 o;
    o.x = f2bf(f.x); o.y = f2bf(f.y); o.z = f2bf(f.z); o.w = f2bf(f.w);
    *(ushortx4*)(qkv + (size_t)y * BTE + (size_t)i * 4) = o;
  } else if (bx < 52224){
    int b2 = bx - 49152;
    int y = b2 >> 10;
    int i = ((b2 & 1023) << 8) + threadIdx.x;          // < NE*NE/4
    const float* src = y == 0 ? w0 : (y == 1 ? w1 : w2);
    floatx4 f = ((const floatx4*)src)[i];
    ushortx4 o;
    o.x = f2bf(f.x); o.y = f2bf(f.y); o.z = f2bf(f.z); o.w = f2bf(f.w);
    *(ushortx4*)(wout + (size_t)y * (NE * NE) + (size_t)i * 4) = o;
  } else {
    int t = ((bx - 52224) << 8) + threadIdx.x;         // 0..65535 words
    const int4* p = (const int4*)(m + (size_t)t * 64);
    unsigned long long w = 0;
    #pragma unroll
    for (int jj = 0; jj < 16; jj++){
      int4 vv = p[jj];
      w |= (unsigned long long)(vv.x != 0) << (jj * 4 + 0);
      w |= (unsigned long long)(vv.y != 0) << (jj * 4 + 1);
      w |= (unsigned long long)(vv.z != 0) << (jj * 4 + 2);
      w |= (unsigned long long)(vv.w != 0) << (jj * 4 + 3);
    }
    bits[t] = w;
  }
}

// ---------------- NT GEMM: C[m,n] = sum_k A[m,k]*B[n,k], all bf16 in ----------------
// Tile 256x256, BK=64, 512 threads = 8 waves (wm=wave>>2 in M, wn=wave&3 in N);
// per-wave 128x64 output = acc[8][4] of 16x16x32 MFMAs.
// LDS 128 KB pipeline region: [dbuf][A|B][khalf] 16 KB units, 64-B rows.
// Chunk swizzle: logical chunk c of row r at physical slot c^((r>>1)&3)
// (verified 0 bank conflicts). Staging: linear-LDS global_load_lds with the
// inverse swizzle on the per-lane GLOBAL address.
// Phase body (r5/r8/r9-verified): {stage 1 unit; ds_read frags;
// [vmcnt]+lgkm0+s_barrier fused; sched_barrier; setprio 16xMFMA}.
// Waits: p2 vmcnt(10) confirms Ak1(t); p4 vmcnt(8) confirms Bk0/Ak0/Bk1(t+1).
// EPI 0: store bf16; if z==2 && trOut: LDS-transpose and store to trOut
//        ([emb][token] per batch) instead — fused V^T.
// EPI 1: e = mask ? exp(v/32) : 0, store bf16, atomic per-row sum.
// EPI 2: fp32 out scaled by 1/rowsum[row].
template<int EPI>
__global__ __launch_bounds__(512, 2) void gemm_nt(
    const unsigned short* __restrict__ A, long strideA,
    const unsigned short* __restrict__ B, long strideB,
    void* __restrict__ Out, long strideOutBytes,
    const unsigned long long* __restrict__ mbits,
    float* __restrict__ rowsums,
    unsigned short* __restrict__ trOut,
    int K, int gx, int gy)
{
  __shared__ __attribute__((aligned(16))) char Lds[135168];  // 128K pipe + pad for epi-transpose
  const int tid = threadIdx.x;
  const int lane = tid & 63, wave = tid >> 6;

  // XCD-aware decode: L%8 = XCD; all gx n-tiles of one A-strip on one XCD.
  int L = blockIdx.x;
  int xcd = L & 7, tt = L >> 3;
  int x = tt % gx;
  int strip = xcd + ((tt / gx) << 3);
  int y = strip % gy, z = strip / gy;
  const int m0 = y << 8, n0 = x << 8;
  const int Nn = gx << 8;

  const unsigned short* Az = A + (size_t)z * strideA;
  const unsigned short* Bz = B + (size_t)z * strideB;

  // Staging: unit = 16 KB = 1024 slots of 16B; thread covers slots tid and
  // tid+512. slot s: r = s>>2 (row; +128 for the second), cs = s&3,
  // logical chunk c = cs ^ ((r>>1)&3)  [invariant under r+128].
  const long rowb  = (long)K * 2;       // bytes per A/B row
  const long rs128 = rowb << 7;         // 128 rows
  const int r0 = tid >> 2;
  const int c0 = (tid & 3) ^ ((r0 >> 1) & 3);
  const char* pA0 = (const char*)Az + (size_t)(m0 + r0) * rowb + (c0 << 4);      // k-half 0
  const char* pA1 = pA0 + 64;                                                    // k-half 1
  const char* pB0 = (const char*)Bz + (size_t)(n0 + r0) * rowb + (c0 << 4);
  const char* pB1 = pB0 + 64;
  const int stg = tid << 4;

  auto stageU = [&](const char*& g, int ldsoff){
    async16(Lds + ldsoff + stg,        g);
    async16(Lds + ldsoff + stg + 8192, g + rs128);
    g += 128;                           // advance one K-tile (BK=64 bf16)
  };

  // Fragment reads: row = (warp base) + mi*16 + lm, logical chunk qd at
  // physical slot qd ^ ((row>>1)&3) = qd ^ ((lm>>1)&3).
  const int lm = lane & 15, qd = lane >> 4;
  const int wm = wave >> 2, wn = wave & 3;          // 2 (M) x 4 (N)
  const int fsw  = (qd ^ ((lm >> 1) & 3)) << 4;
  const int aoff = ((wm << 7) + lm) * 64 + fsw;               // + mi*1024 + kh*16384 + dbuf
  const int boff = 32768 + ((wn << 6) + lm) * 64 + fsw;       // + ni*1024 + kh*16384 + dbuf

  floatx4 acc[8][4];
  floatx4 zero4 = {0.f, 0.f, 0.f, 0.f};
  #pragma unroll
  for (int a = 0; a < 8; a++)
    #pragma unroll
    for (int b = 0; b < 4; b++) acc[a][b] = zero4;

  const int NK = K >> 6;

  // Prologue: tile0 all 4 units, tile1 {B-k0, A-k0, B-k1} (A-k1(1) comes at
  // t=0.p1). vmcnt(6) confirms tile0's 8 loads, leaves tile1's 6 in flight.
  stageU(pB0, 32768);                     // B-k0(0) dbuf0
  stageU(pA0, 0);                         // A-k0(0)
  stageU(pB1, 32768 + 16384);             // B-k1(0)
  stageU(pA1, 16384);                     // A-k1(0)
  stageU(pB0, 65536 + 32768);             // B-k0(1) dbuf1
  stageU(pA0, 65536);                     // A-k0(1)
  stageU(pB1, 65536 + 32768 + 16384);     // B-k1(1)
  asm volatile("s_waitcnt vmcnt(6)\n\ts_barrier" ::: "memory");

  short8 a[4], b[4];
  for (int t = 0; t < NK; ++t){
    const int rb = (t & 1) << 16;         // read dbuf (and t+2 stage dbuf)
    const int sb = rb ^ 65536;            // t+1 stage dbuf

    // ---- phase 1: kh=0, mi 0-3 (+ all B kh=0) ----
    if (t + 1 < NK) stageU(pA1, sb + 16384);
    #pragma unroll
    for (int j = 0; j < 4; j++) a[j] = *(const short8*)(Lds + rb + aoff + j * 1024);
    #pragma unroll
    for (int n = 0; n < 4; n++) b[n] = *(const short8*)(Lds + rb + boff + n * 1024);
    asm volatile("s_waitcnt lgkmcnt(0)\n\ts_barrier" ::: "memory");
    __builtin_amdgcn_sched_barrier(0);
    __builtin_amdgcn_s_setprio(1);
    #pragma unroll
    for (int j = 0; j < 4; j++)
      #pragma unroll
      for (int n = 0; n < 4; n++) MFMA16(acc[j][n], a[j], b[n]);
    __builtin_amdgcn_s_setprio(0);

    // ---- phase 2: kh=0, mi 4-7; vmcnt(10) confirms Ak1(t) for p3 ----
    if (t + 2 < NK) stageU(pB0, rb + 32768);
    #pragma unroll
    for (int j = 0; j < 4; j++) a[j] = *(const short8*)(Lds + rb + aoff + (4 + j) * 1024);
    if (t + 2 < NK)
      asm volatile("s_waitcnt vmcnt(10) lgkmcnt(0)\n\ts_barrier" ::: "memory");
    else if (t + 1 < NK)
      asm volatile("s_waitcnt vmcnt(8) lgkmcnt(0)\n\ts_barrier" ::: "memory");
    else
      asm volatile("s_waitcnt lgkmcnt(0)\n\ts_barrier" ::: "memory");
    __builtin_amdgcn_sched_barrier(0);
    __builtin_amdgcn_s_setprio(1);
    #pragma unroll
    for (int j = 0; j < 4; j++)
      #pragma unroll
      for (int n = 0; n < 4; n++) MFMA16(acc[4 + j][n], a[j], b[n]);
    __builtin_amdgcn_s_setprio(0);

    // ---- phase 3: kh=1, mi 0-3 (+ all B kh=1) ----
    if (t + 2 < NK) stageU(pA0, rb);
    #pragma unroll
    for (int j = 0; j < 4; j++) a[j] = *(const short8*)(Lds + rb + 16384 + aoff + j * 1024);
    #pragma unroll
    for (int n = 0; n < 4; n++) b[n] = *(const short8*)(Lds + rb + 16384 + boff + n * 1024);
    asm volatile("s_waitcnt lgkmcnt(0)\n\ts_barrier" ::: "memory");
    __builtin_amdgcn_sched_barrier(0);
    __builtin_amdgcn_s_setprio(1);
    #pragma unroll
    for (int j = 0; j < 4; j++)
      #pragma unroll
      for (int n = 0; n < 4; n++) MFMA16(acc[j][n], a[j], b[n]);
    __builtin_amdgcn_s_setprio(0);

    // ---- phase 4: kh=1, mi 4-7; vmcnt(8) confirms Bk0/Ak0/Bk1(t+1) ----
    #pragma unroll
    for (int j = 0; j < 4; j++) a[j] = *(const short8*)(Lds + rb + 16384 + aoff + (4 + j) * 1024);
    if (t + 2 < NK){
      stageU(pB1, rb + 32768 + 16384);
      asm volatile("s_waitcnt vmcnt(8) lgkmcnt(0)\n\ts_barrier" ::: "memory");
    } else {
      asm volatile("s_waitcnt vmcnt(0) lgkmcnt(0)\n\ts_barrier" ::: "memory");
    }
    __builtin_amdgcn_sched_barrier(0);
    __builtin_amdgcn_s_setprio(1);
    #pragma unroll
    for (int j = 0; j < 4; j++)
      #pragma unroll
      for (int n = 0; n < 4; n++) MFMA16(acc[4 + j][n], a[j], b[n]);
    __builtin_amdgcn_s_setprio(0);
  }

  // Epilogue. C/D layout: col = lane&15, row = (lane>>4)*4 + i  (m89/m91).
  char* OutZ = (char*)Out + (size_t)z * strideOutBytes;
  const int colbase = n0 + (wn << 6);
  if constexpr (EPI == 1){
    const int wcol = colbase >> 6;
    #pragma unroll
    for (int mi = 0; mi < 8; mi++){
      #pragma unroll
      for (int i = 0; i < 4; i++){
        int row = m0 + (wm << 7) + mi * 16 + qd * 4 + i;
        unsigned long long w = mbits[(size_t)row * (NT / 64) + wcol];
        unsigned short* po = (unsigned short*)OutZ + (size_t)row * Nn + colbase;
        float rsum = 0.f;
        #pragma unroll
        for (int ni = 0; ni < 4; ni++){
          float vv = acc[mi][ni][i];
          float e = ((w >> (ni * 16 + lm)) & 1ull) ? __expf(vv * 0.03125f) : 0.f;
          rsum += e;
          po[ni * 16 + lm] = f2bf(e);
        }
        // reduce across the 16 lanes (lm) of this qd group -> row total (64 cols)
        rsum += __shfl_xor(rsum, 1, 64);
        rsum += __shfl_xor(rsum, 2, 64);
        rsum += __shfl_xor(rsum, 4, 64);
        rsum += __shfl_xor(rsum, 8, 64);
        if (lm == 0) atomicAdd(rowsums + ((size_t)z << 11) + row, rsum);
      }
    }
  } else if constexpr (EPI == 2){
    #pragma unroll
    for (int mi = 0; mi < 8; mi++){
      #pragma unroll
      for (int i = 0; i < 4; i++){
        int row = m0 + (wm << 7) + mi * 16 + qd * 4 + i;
        float inv = 1.0f / rowsums[((size_t)z << 11) + row];
        #pragma unroll
        for (int ni = 0; ni < 4; ni++){
          int col = colbase + ni * 16 + lm;
          ((float*)OutZ)[(size_t)row * Nn + col] = acc[mi][ni][i] * inv;
        }
      }
    }
  } else {
    if (trOut != nullptr && z == 2){
      // Fused V^T: acc -> LDS [colLocal][token] (528-B padded col-rows),
      // then coalesced 16B stores to trOut[b][emb][token].
      #pragma unroll
      for (int mi = 0; mi < 8; mi++){
        int row0 = (wm << 7) + mi * 16 + qd * 4;      // token within tile, %4==0
        #pragma unroll
        for (int ni = 0; ni < 4; ni++){
          int col = (wn << 6) + ni * 16 + lm;          // emb within tile
          unsigned int lo = (unsigned int)f2bf(acc[mi][ni][0]) |
                            ((unsigned int)f2bf(acc[mi][ni][1]) << 16);
          unsigned int hi = (unsigned int)f2bf(acc[mi][ni][2]) |
                            ((unsigned int)f2bf(acc[mi][ni][3]) << 16);
          uint2v p; p.x = lo; p.y = hi;
          *(uint2v*)(Lds + col * 528 + row0 * 2) = p;  // 8B store, 8-aligned
        }
      }
      __syncthreads();
      int bb = m0 >> 11, tb = m0 & 2047;               // batch, token base
      unsigned short* base = trOut + (size_t)bb * NE * NT + (size_t)n0 * NT + tb;
      #pragma unroll
      for (int k2 = 0; k2 < 16; k2++){
        int gid = (k2 << 9) + tid;                     // 0..8191
        int col = gid >> 5, chk = gid & 31;            // 256 cols x 32 chunks
        ushortx8 vv = *(const ushortx8*)(Lds + col * 528 + (chk << 4));
        *(ushortx8*)(base + (size_t)col * NT + (chk << 3)) = vv;
      }
    } else {
      #pragma unroll
      for (int mi = 0; mi < 8; mi++){
        #pragma unroll
        for (int i = 0; i < 4; i++){
          int row = m0 + (wm << 7) + mi * 16 + qd * 4 + i;
          #pragma unroll
          for (int ni = 0; ni < 4; ni++){
            int col = colbase + ni * 16 + lm;
            ((unsigned short*)OutZ)[(size_t)row * Nn + col] = f2bf(acc[mi][ni][i]);
          }
        }
      }
    }
  }
}

extern "C" void kernel_launch(void* const* d_in, const int* in_sizes, int n_in,
                              void* d_out, int out_size, void* d_ws, size_t ws_size,
                              hipStream_t stream){
  const float* q  = (const float*)d_in[0];
  const float* k  = (const float*)d_in[1];
  const float* v  = (const float*)d_in[2];
  const int* mask = (const int*)d_in[3];
  const float* Wq = (const float*)d_in[4];
  const float* Wk = (const float*)d_in[5];
  const float* Wv = (const float*)d_in[6];

  const size_t BTE = (size_t)NB * NT * NE;     // 16,777,216
  unsigned short* ws   = (unsigned short*)d_ws;
  unsigned short* QKVp = ws;                                    // [3][B*T][E] (V slot holds V^T)
  unsigned short* Sb   = ws + 3 * BTE + BTE;                    // [B][T][T]
  unsigned short* Qin  = ws + 3 * BTE;                          // [3][B*T][E] bf16 inputs
  unsigned short* Wb   = ws + 3 * BTE + BTE + (size_t)NB * NT * NT;  // [3][E][E]
  unsigned long long* mbits = (unsigned long long*)(Wb + (size_t)3 * NE * NE);
  // rowsums [NB][NT] f32 (64 KB) overlays Wb (dead after projections).
  float* rowsums = (float*)Wb;

  unsigned short* Qp  = QKVp;
  unsigned short* Kp  = QKVp + BTE;
  unsigned short* VpT = QKVp + 2 * BTE;        // [B][E][T], written by proj epilogue

  // 1) all pre-processing in one dispatch: q/k/v cvt + weight cvt + mask pack
  preall<<<52480, 256, 0, stream>>>(q, k, v, Qin, Wq, Wk, Wv, Wb, mask, mbits);

  // 2) projections: [3 x] (16384 x 1024 x 1024); gx=4, gy=64, gz=3.
  //    z==2 (V) writes V^T into VpT via fused LDS transpose.
  gemm_nt<0><<<768, 512, 0, stream>>>(
      Qin, (long)BTE, Wb, (long)NE * NE,
      QKVp, (long)BTE * 2, nullptr, nullptr, VpT, NE, 4, 64);

  // 3) zero rowsums (Wb dead now; must precede QK^T's atomics)
  hipMemsetAsync(rowsums, 0, (size_t)NB * NT * sizeof(float), stream);

  // 4) S' = mask ? exp(QK^T/32) : 0, + per-row sums; gx=8, gy=8, gz=8
  gemm_nt<1><<<512, 512, 0, stream>>>(
      Qp, (long)NT * NE, Kp, (long)NT * NE,
      Sb, (long)NT * NT * 2, mbits, rowsums, nullptr, NE, 8, 8);

  // 5) O = (S' V) / rowsum; gx=4, gy=8, gz=8, fp32 out
  gemm_nt<2><<<256, 512, 0, stream>>>(
      Sb, (long)NT * NT, VpT, (long)NE * NT,
      d_out, (long)NT * NE * 4, nullptr, rowsums, nullptr, NT, 4, 8);
}

// Round 10
// 492.671 us; speedup vs baseline: 4.5911x; 1.0373x over previous
//
#include <hip/hip_runtime.h>
#include <hip/hip_bf16.h>

// B=8, T=2048, E=1024 single-head attention, bf16 MFMA pipeline, round 12:
// = round 9 (best verified: 498 µs; preall merge of r11 reverted) with a new
// 2-D XCD-contiguous tile decode: inner 4(x)x2(y) rectangles, yb-fastest
// groups, R = xcd*Rper + g. For QK^T and PV this pins batch z == xcd, so
// each XCD's K-matrix / V^T (4 MB) stays resident in its private L2 for the
// whole dispatch (~3x cut in L3->L2 panel traffic vs 1-D strips). GEMM
// K-loop, epilogues, workspace identical to r9 (schedule lever exhausted:
// r5/r7/r8/r9 all 109-114 µs; r10's 2-blocks/CU spilled the accumulator).
typedef __attribute__((ext_vector_type(8))) short short8;
typedef __attribute__((ext_vector_type(8))) unsigned short ushortx8;
typedef __attribute__((ext_vector_type(4))) unsigned short ushortx4;
typedef __attribute__((ext_vector_type(4))) float floatx4;
typedef __attribute__((ext_vector_type(2))) unsigned int uint2v;

#define NB 8
#define NT 2048
#define NE 1024

__device__ __forceinline__ unsigned short f2bf(float f){
  unsigned int u = __builtin_bit_cast(unsigned int, f);
  u += 0x7FFFu + ((u >> 16) & 1u);          // RNE; inputs finite
  return (unsigned short)(u >> 16);
}

__device__ __forceinline__ void async16(void* lds, const void* g){
  __builtin_amdgcn_global_load_lds(
      (const __attribute__((address_space(1))) unsigned int*)g,
      (__attribute__((address_space(3))) unsigned int*)lds, 16, 0, 0);
}

#define MFMA16(d, va, vb) \
  d = __builtin_amdgcn_mfma_f32_16x16x32_bf16(va, vb, d, 0, 0, 0)

// ---------------- fp32 -> bf16 convert, 3 sources (q,k,v) ----------------
__global__ __launch_bounds__(256) void cvt3(const float* __restrict__ a0,
                                            const float* __restrict__ a1,
                                            const float* __restrict__ a2,
                                            unsigned short* __restrict__ out,
                                            int n4_per){
  const float* src = blockIdx.y == 0 ? a0 : (blockIdx.y == 1 ? a1 : a2);
  unsigned short* dst = out + (size_t)blockIdx.y * (size_t)n4_per * 4;
  int i = blockIdx.x * 256 + threadIdx.x;
  if (i < n4_per){
    floatx4 f = ((const floatx4*)src)[i];
    ushortx4 o;
    o.x = f2bf(f.x); o.y = f2bf(f.y); o.z = f2bf(f.z); o.w = f2bf(f.w);
    *(ushortx4*)(dst + (size_t)i * 4) = o;
  }
}

// ------ prep: weights fp32->bf16 (blocks 0..3071) + mask bitpack (3072..3327) ------
__global__ __launch_bounds__(256) void prep(const float* __restrict__ w0,
                                            const float* __restrict__ w1,
                                            const float* __restrict__ w2,
                                            unsigned short* __restrict__ wout,
                                            const int* __restrict__ m,
                                            unsigned long long* __restrict__ bits){
  int bx = blockIdx.x;
  if (bx < 3072){
    int y = bx >> 10;
    int i = ((bx & 1023) << 8) + threadIdx.x;         // 0..262143 per weight
    const float* src = y == 0 ? w0 : (y == 1 ? w1 : w2);
    floatx4 f = ((const floatx4*)src)[i];
    ushortx4 o;
    o.x = f2bf(f.x); o.y = f2bf(f.y); o.z = f2bf(f.z); o.w = f2bf(f.w);
    *(ushortx4*)(wout + (size_t)y * (NE * NE) + (size_t)i * 4) = o;
  } else {
    int t = ((bx - 3072) << 8) + threadIdx.x;         // 0..65535 words
    const int4* p = (const int4*)(m + (size_t)t * 64);
    unsigned long long w = 0;
    #pragma unroll
    for (int jj = 0; jj < 16; jj++){
      int4 v = p[jj];
      w |= (unsigned long long)(v.x != 0) << (jj * 4 + 0);
      w |= (unsigned long long)(v.y != 0) << (jj * 4 + 1);
      w |= (unsigned long long)(v.z != 0) << (jj * 4 + 2);
      w |= (unsigned long long)(v.w != 0) << (jj * 4 + 3);
    }
    bits[t] = w;
  }
}

// ---------------- NT GEMM: C[m,n] = sum_k A[m,k]*B[n,k], all bf16 in ----------------
// Tile 256x256, BK=64, 512 threads = 8 waves (wm=wave>>2 in M, wn=wave&3 in N);
// per-wave 128x64 output = acc[8][4] of 16x16x32 MFMAs.
// LDS 128 KB pipeline region: [dbuf][A|B][khalf] 16 KB units, 64-B rows.
// Chunk swizzle: logical chunk c of row r at physical slot c^((r>>1)&3)
// (verified 0 bank conflicts). Staging: linear-LDS global_load_lds with the
// inverse swizzle on the per-lane GLOBAL address.
// Block decode (NEW, r12): xcd = L&7; inner 4(x)x2(y) rectangle; groups
// yb-fastest; R = xcd*Rper + g -> XCD-contiguous rectangle ranges. For
// QK^T (2x4x8 groups) and PV (1x4x8) this yields z == xcd: per-XCD L2
// pins that batch's B panels. Requires gx%4==0, gy%2==0, total%8==0.
// Phase body (r5/r8/r9-verified): {stage 1 unit; ds_read frags;
// [vmcnt]+lgkm0+s_barrier fused; sched_barrier; setprio 16xMFMA}.
// Waits: p2 vmcnt(10) confirms Ak1(t); p4 vmcnt(8) confirms Bk0/Ak0/Bk1(t+1).
// EPI 0: store bf16; if z==2 && trOut: LDS-transpose and store to trOut
//        ([emb][token] per batch) instead — fused V^T.
// EPI 1: e = mask ? exp(v/32) : 0, store bf16, atomic per-row sum.
// EPI 2: fp32 out scaled by 1/rowsum[row].
template<int EPI>
__global__ __launch_bounds__(512, 2) void gemm_nt(
    const unsigned short* __restrict__ A, long strideA,
    const unsigned short* __restrict__ B, long strideB,
    void* __restrict__ Out, long strideOutBytes,
    const unsigned long long* __restrict__ mbits,
    float* __restrict__ rowsums,
    unsigned short* __restrict__ trOut,
    int K, int gx, int gy, int gz)
{
  __shared__ __attribute__((aligned(16))) char Lds[135168];  // 128K pipe + pad for epi-transpose
  const int tid = threadIdx.x;
  const int lane = tid & 63, wave = tid >> 6;

  // 2-D XCD-contiguous decode (see header).
  int L = blockIdx.x;
  int xcd = L & 7, t = L >> 3;
  int inner = t & 7;                    // ox = inner&3, oy = inner>>2
  int g = t >> 3;
  int nx = gx >> 2, ny = gy >> 1;
  int perz = nx * ny;
  int Rper = (perz * gz) >> 3;          // rectangle-groups per XCD
  int R = xcd * Rper + g;
  int z = R / perz, rem = R % perz;
  int yb = rem % ny, X = rem / ny;      // yb fastest: consecutive groups share B
  int x = (X << 2) + (inner & 3);
  int y = (yb << 1) + (inner >> 2);
  const int m0 = y << 8, n0 = x << 8;
  const int Nn = gx << 8;

  const unsigned short* Az = A + (size_t)z * strideA;
  const unsigned short* Bz = B + (size_t)z * strideB;

  // Staging: unit = 16 KB = 1024 slots of 16B; thread covers slots tid and
  // tid+512. slot s: r = s>>2 (row; +128 for the second), cs = s&3,
  // logical chunk c = cs ^ ((r>>1)&3)  [invariant under r+128].
  const long rowb  = (long)K * 2;       // bytes per A/B row
  const long rs128 = rowb << 7;         // 128 rows
  const int r0 = tid >> 2;
  const int c0 = (tid & 3) ^ ((r0 >> 1) & 3);
  const char* pA0 = (const char*)Az + (size_t)(m0 + r0) * rowb + (c0 << 4);      // k-half 0
  const char* pA1 = pA0 + 64;                                                    // k-half 1
  const char* pB0 = (const char*)Bz + (size_t)(n0 + r0) * rowb + (c0 << 4);
  const char* pB1 = pB0 + 64;
  const int stg = tid << 4;

  auto stageU = [&](const char*& gp, int ldsoff){
    async16(Lds + ldsoff + stg,        gp);
    async16(Lds + ldsoff + stg + 8192, gp + rs128);
    gp += 128;                          // advance one K-tile (BK=64 bf16)
  };

  // Fragment reads: row = (warp base) + mi*16 + lm, logical chunk qd at
  // physical slot qd ^ ((row>>1)&3) = qd ^ ((lm>>1)&3).
  const int lm = lane & 15, qd = lane >> 4;
  const int wm = wave >> 2, wn = wave & 3;          // 2 (M) x 4 (N)
  const int fsw  = (qd ^ ((lm >> 1) & 3)) << 4;
  const int aoff = ((wm << 7) + lm) * 64 + fsw;               // + mi*1024 + kh*16384 + dbuf
  const int boff = 32768 + ((wn << 6) + lm) * 64 + fsw;       // + ni*1024 + kh*16384 + dbuf

  floatx4 acc[8][4];
  floatx4 zero4 = {0.f, 0.f, 0.f, 0.f};
  #pragma unroll
  for (int a = 0; a < 8; a++)
    #pragma unroll
    for (int b = 0; b < 4; b++) acc[a][b] = zero4;

  const int NK = K >> 6;

  // Prologue: tile0 all 4 units, tile1 {B-k0, A-k0, B-k1} (A-k1(1) comes at
  // t=0.p1). vmcnt(6) confirms tile0's 8 loads, leaves tile1's 6 in flight.
  stageU(pB0, 32768);                     // B-k0(0) dbuf0
  stageU(pA0, 0);                         // A-k0(0)
  stageU(pB1, 32768 + 16384);             // B-k1(0)
  stageU(pA1, 16384);                     // A-k1(0)
  stageU(pB0, 65536 + 32768);             // B-k0(1) dbuf1
  stageU(pA0, 65536);                     // A-k0(1)
  stageU(pB1, 65536 + 32768 + 16384);     // B-k1(1)
  asm volatile("s_waitcnt vmcnt(6)\n\ts_barrier" ::: "memory");

  short8 a[4], b[4];
  for (int tt = 0; tt < NK; ++tt){
    const int rb = (tt & 1) << 16;        // read dbuf (and t+2 stage dbuf)
    const int sb = rb ^ 65536;            // t+1 stage dbuf

    // ---- phase 1: kh=0, mi 0-3 (+ all B kh=0) ----
    if (tt + 1 < NK) stageU(pA1, sb + 16384);
    #pragma unroll
    for (int j = 0; j < 4; j++) a[j] = *(const short8*)(Lds + rb + aoff + j * 1024);
    #pragma unroll
    for (int n = 0; n < 4; n++) b[n] = *(const short8*)(Lds + rb + boff + n * 1024);
    asm volatile("s_waitcnt lgkmcnt(0)\n\ts_barrier" ::: "memory");
    __builtin_amdgcn_sched_barrier(0);
    __builtin_amdgcn_s_setprio(1);
    #pragma unroll
    for (int j = 0; j < 4; j++)
      #pragma unroll
      for (int n = 0; n < 4; n++) MFMA16(acc[j][n], a[j], b[n]);
    __builtin_amdgcn_s_setprio(0);

    // ---- phase 2: kh=0, mi 4-7; vmcnt(10) confirms Ak1(t) for p3 ----
    if (tt + 2 < NK) stageU(pB0, rb + 32768);
    #pragma unroll
    for (int j = 0; j < 4; j++) a[j] = *(const short8*)(Lds + rb + aoff + (4 + j) * 1024);
    if (tt + 2 < NK)
      asm volatile("s_waitcnt vmcnt(10) lgkmcnt(0)\n\ts_barrier" ::: "memory");
    else if (tt + 1 < NK)
      asm volatile("s_waitcnt vmcnt(8) lgkmcnt(0)\n\ts_barrier" ::: "memory");
    else
      asm volatile("s_waitcnt lgkmcnt(0)\n\ts_barrier" ::: "memory");
    __builtin_amdgcn_sched_barrier(0);
    __builtin_amdgcn_s_setprio(1);
    #pragma unroll
    for (int j = 0; j < 4; j++)
      #pragma unroll
      for (int n = 0; n < 4; n++) MFMA16(acc[4 + j][n], a[j], b[n]);
    __builtin_amdgcn_s_setprio(0);

    // ---- phase 3: kh=1, mi 0-3 (+ all B kh=1) ----
    if (tt + 2 < NK) stageU(pA0, rb);
    #pragma unroll
    for (int j = 0; j < 4; j++) a[j] = *(const short8*)(Lds + rb + 16384 + aoff + j * 1024);
    #pragma unroll
    for (int n = 0; n < 4; n++) b[n] = *(const short8*)(Lds + rb + 16384 + boff + n * 1024);
    asm volatile("s_waitcnt lgkmcnt(0)\n\ts_barrier" ::: "memory");
    __builtin_amdgcn_sched_barrier(0);
    __builtin_amdgcn_s_setprio(1);
    #pragma unroll
    for (int j = 0; j < 4; j++)
      #pragma unroll
      for (int n = 0; n < 4; n++) MFMA16(acc[j][n], a[j], b[n]);
    __builtin_amdgcn_s_setprio(0);

    // ---- phase 4: kh=1, mi 4-7; vmcnt(8) confirms Bk0/Ak0/Bk1(t+1) ----
    #pragma unroll
    for (int j = 0; j < 4; j++) a[j] = *(const short8*)(Lds + rb + 16384 + aoff + (4 + j) * 1024);
    if (tt + 2 < NK){
      stageU(pB1, rb + 32768 + 16384);
      asm volatile("s_waitcnt vmcnt(8) lgkmcnt(0)\n\ts_barrier" ::: "memory");
    } else {
      asm volatile("s_waitcnt vmcnt(0) lgkmcnt(0)\n\ts_barrier" ::: "memory");
    }
    __builtin_amdgcn_sched_barrier(0);
    __builtin_amdgcn_s_setprio(1);
    #pragma unroll
    for (int j = 0; j < 4; j++)
      #pragma unroll
      for (int n = 0; n < 4; n++) MFMA16(acc[4 + j][n], a[j], b[n]);
    __builtin_amdgcn_s_setprio(0);
  }

  // Epilogue. C/D layout: col = lane&15, row = (lane>>4)*4 + i  (m89/m91).
  char* OutZ = (char*)Out + (size_t)z * strideOutBytes;
  const int colbase = n0 + (wn << 6);
  if constexpr (EPI == 1){
    const int wcol = colbase >> 6;
    #pragma unroll
    for (int mi = 0; mi < 8; mi++){
      #pragma unroll
      for (int i = 0; i < 4; i++){
        int row = m0 + (wm << 7) + mi * 16 + qd * 4 + i;
        unsigned long long w = mbits[(size_t)row * (NT / 64) + wcol];
        unsigned short* po = (unsigned short*)OutZ + (size_t)row * Nn + colbase;
        float rsum = 0.f;
        #pragma unroll
        for (int ni = 0; ni < 4; ni++){
          float vv = acc[mi][ni][i];
          float e = ((w >> (ni * 16 + lm)) & 1ull) ? __expf(vv * 0.03125f) : 0.f;
          rsum += e;
          po[ni * 16 + lm] = f2bf(e);
        }
        // reduce across the 16 lanes (lm) of this qd group -> row total (64 cols)
        rsum += __shfl_xor(rsum, 1, 64);
        rsum += __shfl_xor(rsum, 2, 64);
        rsum += __shfl_xor(rsum, 4, 64);
        rsum += __shfl_xor(rsum, 8, 64);
        if (lm == 0) atomicAdd(rowsums + ((size_t)z << 11) + row, rsum);
      }
    }
  } else if constexpr (EPI == 2){
    #pragma unroll
    for (int mi = 0; mi < 8; mi++){
      #pragma unroll
      for (int i = 0; i < 4; i++){
        int row = m0 + (wm << 7) + mi * 16 + qd * 4 + i;
        float inv = 1.0f / rowsums[((size_t)z << 11) + row];
        #pragma unroll
        for (int ni = 0; ni < 4; ni++){
          int col = colbase + ni * 16 + lm;
          ((float*)OutZ)[(size_t)row * Nn + col] = acc[mi][ni][i] * inv;
        }
      }
    }
  } else {
    if (trOut != nullptr && z == 2){
      // Fused V^T: acc -> LDS [colLocal][token] (528-B padded col-rows),
      // then coalesced 16B stores to trOut[b][emb][token].
      #pragma unroll
      for (int mi = 0; mi < 8; mi++){
        int row0 = (wm << 7) + mi * 16 + qd * 4;      // token within tile, %4==0
        #pragma unroll
        for (int ni = 0; ni < 4; ni++){
          int col = (wn << 6) + ni * 16 + lm;          // emb within tile
          unsigned int lo = (unsigned int)f2bf(acc[mi][ni][0]) |
                            ((unsigned int)f2bf(acc[mi][ni][1]) << 16);
          unsigned int hi = (unsigned int)f2bf(acc[mi][ni][2]) |
                            ((unsigned int)f2bf(acc[mi][ni][3]) << 16);
          uint2v p; p.x = lo; p.y = hi;
          *(uint2v*)(Lds + col * 528 + row0 * 2) = p;  // 8B store, 8-aligned
        }
      }
      __syncthreads();
      int bb = m0 >> 11, tb = m0 & 2047;               // batch, token base
      unsigned short* base = trOut + (size_t)bb * NE * NT + (size_t)n0 * NT + tb;
      #pragma unroll
      for (int k2 = 0; k2 < 16; k2++){
        int gid = (k2 << 9) + tid;                     // 0..8191
        int col = gid >> 5, chk = gid & 31;            // 256 cols x 32 chunks
        ushortx8 vv = *(const ushortx8*)(Lds + col * 528 + (chk << 4));
        *(ushortx8*)(base + (size_t)col * NT + (chk << 3)) = vv;
      }
    } else {
      #pragma unroll
      for (int mi = 0; mi < 8; mi++){
        #pragma unroll
        for (int i = 0; i < 4; i++){
          int row = m0 + (wm << 7) + mi * 16 + qd * 4 + i;
          #pragma unroll
          for (int ni = 0; ni < 4; ni++){
            int col = colbase + ni * 16 + lm;
            ((unsigned short*)OutZ)[(size_t)row * Nn + col] = f2bf(acc[mi][ni][i]);
          }
        }
      }
    }
  }
}

extern "C" void kernel_launch(void* const* d_in, const int* in_sizes, int n_in,
                              void* d_out, int out_size, void* d_ws, size_t ws_size,
                              hipStream_t stream){
  const float* q  = (const float*)d_in[0];
  const float* k  = (const float*)d_in[1];
  const float* v  = (const float*)d_in[2];
  const int* mask = (const int*)d_in[3];
  const float* Wq = (const float*)d_in[4];
  const float* Wk = (const float*)d_in[5];
  const float* Wv = (const float*)d_in[6];

  const size_t BTE = (size_t)NB * NT * NE;     // 16,777,216
  unsigned short* ws   = (unsigned short*)d_ws;
  unsigned short* QKVp = ws;                                    // [3][B*T][E] (V slot holds V^T)
  unsigned short* Sb   = ws + 3 * BTE + BTE;                    // [B][T][T]
  unsigned short* Qin  = ws + 3 * BTE;                          // [3][B*T][E] bf16 inputs
  unsigned short* Wb   = ws + 3 * BTE + BTE + (size_t)NB * NT * NT;  // [3][E][E]
  unsigned long long* mbits = (unsigned long long*)(Wb + (size_t)3 * NE * NE);
  // rowsums [NB][NT] f32 (64 KB) overlays Wb (dead after projections).
  float* rowsums = (float*)Wb;

  unsigned short* Qp  = QKVp;
  unsigned short* Kp  = QKVp + BTE;
  unsigned short* VpT = QKVp + 2 * BTE;        // [B][E][T], written by proj epilogue

  // 1) fp32 -> bf16: inputs q,k,v (Qin aliases the region later used by Sb)
  cvt3<<<dim3(16384, 3), 256, 0, stream>>>(q, k, v, Qin, (int)(BTE / 4));
  // 2) weights -> bf16 + mask -> bitmask, one dispatch
  prep<<<3328, 256, 0, stream>>>(Wq, Wk, Wv, Wb, mask, mbits);

  // 3) projections: [3 x] (16384 x 1024 x 1024); gx=4, gy=64, gz=3.
  //    z==2 (V) writes V^T into VpT via fused LDS transpose.
  gemm_nt<0><<<768, 512, 0, stream>>>(
      Qin, (long)BTE, Wb, (long)NE * NE,
      QKVp, (long)BTE * 2, nullptr, nullptr, VpT, NE, 4, 64, 3);

  // 4) zero rowsums (Wb dead now; must precede QK^T's atomics)
  hipMemsetAsync(rowsums, 0, (size_t)NB * NT * sizeof(float), stream);

  // 5) S' = mask ? exp(QK^T/32) : 0, + per-row sums; gx=8, gy=8, gz=8.
  //    New decode pins z == xcd: K-matrix of batch z L2-resident per XCD.
  gemm_nt<1><<<512, 512, 0, stream>>>(
      Qp, (long)NT * NE, Kp, (long)NT * NE,
      Sb, (long)NT * NT * 2, mbits, rowsums, nullptr, NE, 8, 8, 8);

  // 6) O = (S' V) / rowsum; gx=4, gy=8, gz=8, fp32 out; z == xcd pins V^T.
  gemm_nt<2><<<256, 512, 0, stream>>>(
      Sb, (long)NT * NT, VpT, (long)NE * NT,
      d_out, (long)NT * NE * 4, nullptr, rowsums, nullptr, NT, 4, 8, 8);
}